// Round 4
// baseline (960.162 us; speedup 1.0000x reference)
//
#include <hip/hip_runtime.h>
#include <stdint.h>

#define NUM_SEQS 4
#define SEQ_LEN  4096
#define HIDDEN   2048
#define CONV_DIM 2048
#define NTOK     (NUM_SEQS * SEQ_LEN)
#define N3D      (3 * CONV_DIM)

typedef unsigned short u16;
typedef unsigned int   u32;
typedef __bf16 bf16x8 __attribute__((ext_vector_type(8)));
typedef float  f32x16 __attribute__((ext_vector_type(16)));

__device__ __forceinline__ u16 f2bf(float f) {
  union { float f; u32 u; } v; v.f = f;
  u32 u = v.u;
  u += 0x7fffu + ((u >> 16) & 1u);   // round-to-nearest-even
  return (u16)(u >> 16);
}

__device__ __forceinline__ void async16(const void* g, void* l) {
  __builtin_amdgcn_global_load_lds(
      (const __attribute__((address_space(1))) u32*)g,
      (__attribute__((address_space(3))) u32*)l, 16, 0, 0);
}

// ---------------- fp32 -> bf16 cast (vectorized) ----------------
__global__ __launch_bounds__(256) void cast_f32_bf16(
    const float* __restrict__ in, u16* __restrict__ out, int n4)
{
  int i = blockIdx.x * 256 + threadIdx.x;
  if (i >= n4) return;
  float4 f = ((const float4*)in)[i];
  ushort4 o;
  o.x = f2bf(f.x); o.y = f2bf(f.y); o.z = f2bf(f.z); o.w = f2bf(f.w);
  ((ushort4*)out)[i] = o;
}

// ---------------- bf16 GEMM, C = A[M,K] * B[N,K]^T ----------------
// 256x256 tile, BK=32, 8 waves (2M x 4N), per-wave 128x64 as 4x2 frags of
// v_mfma_f32_32x32x16_bf16. Frag layouts (r1-r3 verified):
//   A/B: X[row=lane&31][k=8*(lane>>5)+j]; C/D: col=lane&31,
//   row=(r&3)+8*(r>>2)+4*(lane>>5).
// FRAGMENT-LINEAR LDS (r3, measured 0 bank conflicts): each 32row x 16k frag
// = contiguous 1KB; lane l reads byte l*16. Tile = 16 frags (8 rowBlks x 2 ks)
// = 16 KB. A double-buffered (2), B TRIPLE-buffered (3) -> 80 KiB LDS.
//
// READ-AHEAD PIPELINE (round-4 change): r3 counters showed conflicts=0 but
// MfmaUtil stuck at 40% -- phase-serial ds_reads add to MFMA time (LDS pipe
// ~112 B/cyc/CU measured). Now every ds_read is issued >=1 phase before its
// consuming MFMA and lands during other quadrants' MFMA:
//   p1: stage A(t+1)->bufA^1; read b1(t), a23(t);  bar; MFMA q00 (a01,b0[u])
//   p2:                                            bar; MFMA q01 (a01,b1)
//   p3: stage B(t+2)->bNN; vmcnt(2); bar;
//       read a01(t+1)<-bufA^1, b0[u^1](t+1)<-bN;        MFMA q11 (a23,b1)
//   p4:                                            bar; MFMA q10 (a23,b0[u])
// Liveness (order q00,q01,q11,q10): a01 dead p3-p4, a23 dead p1-p2, b1 dead
// p4-p1 -> single-banked; b0 spans p1..p4 -> double-banked (b0F[2]).
// vmcnt(2) at p3 leaves exactly B(t+2) in flight => A(t+1),B(t+1) landed;
// the following s_barrier publishes ALL waves' staging before the reads.
// Overwrite safety: every LDS region staged is >=2 barriers after its last
// reader's consuming MFMA (checked per-buffer, see r4 notes).
template<bool OUT_BF16>
__global__ __launch_bounds__(512, 2) void gemm256_bt(
    const u16* __restrict__ A, const u16* __restrict__ B, void* __restrict__ Cv,
    const int M, const int N, const int K)
{
  __shared__ u16 sm[40960];            // A: 2x8192 u16, B: 3x8192 u16 (80 KiB)
  u16* ldsA = &sm[0];
  u16* ldsB = &sm[16384];

  const int tid  = threadIdx.x;
  const int lane = tid & 63;
  const int wave = tid >> 6;
  const int l32  = lane & 31;
  const int hl   = lane >> 5;
  const int wm   = wave >> 2;          // 0..1
  const int wn   = wave & 3;           // 0..3
  (void)M;

  // T1: bijective XCD swizzle (nwg % 8 == 0 for all our launches)
  const int gx  = gridDim.x;
  const int nwg = gx * gridDim.y;
  const int orig = blockIdx.y * gx + blockIdx.x;
  const int cpx  = nwg >> 3;
  const int swz  = (orig & 7) * cpx + (orig >> 3);
  const int nBase = (swz % gx) * 256;
  const int mBase = (swz / gx) * 256;

  const int NT = K >> 5;               // K-tiles of 32 (NT=64, even)

  // ---- staging (fragment-linear): thread fills slot tid (rowBlk 0-3) and
  // tid+512 (rowBlk 4-7). slot s: rowBlk=(s>>7), row_in=s&31, ks=(s>>6)&1,
  // hl=(s>>5)&1 -> global col = ks*16+hl*8.
  const int rowS = ((tid >> 7) & 3) * 32 + (tid & 31);
  const int kcol = ((tid >> 6) & 1) * 16 + ((tid >> 5) & 1) * 8;
  const u16* aTB = A + (size_t)(mBase + rowS) * K + kcol;
  const u16* bTB = B + (size_t)(nBase + rowS) * K + kcol;
  const size_t C1 = (size_t)128 * K;   // +128 rows for slot tid+512

#define STAGE_A(bsel, tl) do {                                   \
    u16* _d = ldsA + (bsel) * 8192 + tid * 8;                    \
    const u16* _s = aTB + (size_t)(tl) * 32;                     \
    async16(_s, _d); async16(_s + C1, _d + 4096);                \
  } while (0)
#define STAGE_B(bptr, tl) do {                                   \
    u16* _d = (bptr) + tid * 8;                                  \
    const u16* _s = bTB + (size_t)(tl) * 32;                     \
    async16(_s, _d); async16(_s + C1, _d + 4096);                \
  } while (0)

  // ---- fragment reads: contiguous 1KB per (rowBlk g, ks) ----
  const int lo = lane * 8;
#define LDA(g, ks, bsel) (*(const bf16x8*)&ldsA[(bsel) * 8192 + ((g) * 2 + (ks)) * 512 + lo])
#define LDB(g, ks, bptr) (*(const bf16x8*)&(bptr)[((g) * 2 + (ks)) * 512 + lo])
#define MFMA(a, b, c) __builtin_amdgcn_mfma_f32_32x32x16_bf16((a), (b), (c), 0, 0, 0)

  f32x16 acc[4][2];
#pragma unroll
  for (int i = 0; i < 4; ++i)
#pragma unroll
    for (int j = 0; j < 2; ++j)
#pragma unroll
      for (int r = 0; r < 16; ++r) acc[i][j][r] = 0.f;

  // B triple-buffer rotation: bC=B(t), bN=B(t+1), bNN=stage target B(t+2)
  u16* bC  = ldsB;
  u16* bN  = ldsB + 8192;
  u16* bNN = ldsB + 16384;

  // ---- prologue: A(0), B(0), B(1); drain A0,B0 (leave B1 in flight) ----
  STAGE_A(0, 0);
  STAGE_B(bC, 0);
  STAGE_B(bN, 1);
  asm volatile("s_waitcnt vmcnt(2)" ::: "memory");
  __builtin_amdgcn_s_barrier();
  __builtin_amdgcn_sched_barrier(0);

  bf16x8 a01F[2][2], a23F[2][2], b0F[2][2], b1F[2];
#pragma unroll
  for (int mt = 0; mt < 2; ++mt)
#pragma unroll
    for (int ks = 0; ks < 2; ++ks)
      a01F[mt][ks] = LDA(wm * 4 + mt, ks, 0);
#pragma unroll
  for (int ks = 0; ks < 2; ++ks) b0F[0][ks] = LDB(wn * 2, ks, bC);

  for (int t2 = 0; t2 < NT; t2 += 2) {
#pragma unroll
    for (int u = 0; u < 2; ++u) {      // u == t & 1 (static)
      const int t = t2 + u;

      // ---------- phase 1: stage A(t+1); read b1(t), a23(t); MFMA q00 ----
      if (t + 1 < NT) STAGE_A(u ^ 1, t + 1);
#pragma unroll
      for (int ks = 0; ks < 2; ++ks) b1F[ks] = LDB(wn * 2 + 1, ks, bC);
#pragma unroll
      for (int mt = 0; mt < 2; ++mt)
#pragma unroll
        for (int ks = 0; ks < 2; ++ks) a23F[mt][ks] = LDA(wm * 4 + 2 + mt, ks, u);
      __builtin_amdgcn_sched_barrier(0);
      __builtin_amdgcn_s_barrier();
      __builtin_amdgcn_sched_barrier(0);
      __builtin_amdgcn_s_setprio(1);
#pragma unroll
      for (int ks = 0; ks < 2; ++ks) {
        acc[0][0] = MFMA(a01F[0][ks], b0F[u][ks], acc[0][0]);
        acc[1][0] = MFMA(a01F[1][ks], b0F[u][ks], acc[1][0]);
      }
      __builtin_amdgcn_s_setprio(0);

      // ---------- phase 2: MFMA q01 ----------
      __builtin_amdgcn_sched_barrier(0);
      __builtin_amdgcn_s_barrier();
      __builtin_amdgcn_sched_barrier(0);
      __builtin_amdgcn_s_setprio(1);
#pragma unroll
      for (int ks = 0; ks < 2; ++ks) {
        acc[0][1] = MFMA(a01F[0][ks], b1F[ks], acc[0][1]);
        acc[1][1] = MFMA(a01F[1][ks], b1F[ks], acc[1][1]);
      }
      __builtin_amdgcn_s_setprio(0);

      // ---------- phase 3: stage B(t+2); ckpt; read a01(t+1),b0(t+1); q11 --
      if (t + 2 < NT) {
        STAGE_B(bNN, t + 2);
        asm volatile("s_waitcnt vmcnt(2)" ::: "memory");
      } else {
        asm volatile("s_waitcnt vmcnt(0)" ::: "memory");
      }
      __builtin_amdgcn_sched_barrier(0);
      __builtin_amdgcn_s_barrier();
      __builtin_amdgcn_sched_barrier(0);
      if (t + 1 < NT) {
#pragma unroll
        for (int mt = 0; mt < 2; ++mt)
#pragma unroll
          for (int ks = 0; ks < 2; ++ks)
            a01F[mt][ks] = LDA(wm * 4 + mt, ks, u ^ 1);
#pragma unroll
        for (int ks = 0; ks < 2; ++ks) b0F[u ^ 1][ks] = LDB(wn * 2, ks, bN);
      }
      __builtin_amdgcn_s_setprio(1);
#pragma unroll
      for (int ks = 0; ks < 2; ++ks) {
        acc[2][1] = MFMA(a23F[0][ks], b1F[ks], acc[2][1]);
        acc[3][1] = MFMA(a23F[1][ks], b1F[ks], acc[3][1]);
      }
      __builtin_amdgcn_s_setprio(0);

      // ---------- phase 4: MFMA q10 ----------
      __builtin_amdgcn_sched_barrier(0);
      __builtin_amdgcn_s_barrier();
      __builtin_amdgcn_sched_barrier(0);
      __builtin_amdgcn_s_setprio(1);
#pragma unroll
      for (int ks = 0; ks < 2; ++ks) {
        acc[2][0] = MFMA(a23F[0][ks], b0F[u][ks], acc[2][0]);
        acc[3][0] = MFMA(a23F[1][ks], b0F[u][ks], acc[3][0]);
      }
      __builtin_amdgcn_s_setprio(0);

      // rotate B buffers
      u16* _tmp = bC; bC = bN; bN = bNN; bNN = _tmp;
    }
  }
#undef STAGE_A
#undef STAGE_B
#undef LDA
#undef LDB
#undef MFMA

  // ---- epilogue: C/D col=lane&31, row=(r&3)+8*(r>>2)+4*(lane>>5) ----
#pragma unroll
  for (int mt = 0; mt < 4; ++mt) {
#pragma unroll
    for (int nt = 0; nt < 2; ++nt) {
      const int col = nBase + wn * 64 + nt * 32 + l32;
#pragma unroll
      for (int r = 0; r < 16; ++r) {
        const int row = mBase + wm * 128 + mt * 32 + (r & 3) + 8 * (r >> 2) + 4 * hl;
        if (OUT_BF16)
          ((u16*)Cv)[(size_t)row * N + col] = f2bf(acc[mt][nt][r]);
        else
          ((float*)Cv)[(size_t)row * N + col] = acc[mt][nt][r];
      }
    }
  }
}

// ---------------- causal depthwise conv (K=4) + gating ----------------
#define TT 32
__global__ __launch_bounds__(256) void conv_gate(
    const u16* __restrict__ bcx, const float* __restrict__ convw,
    u16* __restrict__ y, float* __restrict__ states)
{
  const int tid = threadIdx.x;
  const int d8  = tid * 8;
  const int s   = blockIdx.y;
  const int t0  = blockIdx.x * TT;

  float w0[8], w1[8], w2[8], w3[8];
#pragma unroll
  for (int j = 0; j < 8; ++j) {
    float4 wv = *(const float4*)&convw[(d8 + j) * 4];
    w0[j] = wv.x; w1[j] = wv.y; w2[j] = wv.z; w3[j] = wv.w;
  }

  float win0[8], win1[8], win2[8];
  if (t0 == 0) {
#pragma unroll
    for (int j = 0; j < 8; ++j) { win0[j] = 0.f; win1[j] = 0.f; win2[j] = 0.f; }
  } else {
    const u16* r0 = bcx + (size_t)(s * SEQ_LEN + t0 - 3) * N3D + d8;
    bf16x8 b0 = *(const bf16x8*)(r0);
    bf16x8 x0 = *(const bf16x8*)(r0 + 2 * CONV_DIM);
    bf16x8 b1 = *(const bf16x8*)(r0 + N3D);
    bf16x8 x1 = *(const bf16x8*)(r0 + N3D + 2 * CONV_DIM);
    bf16x8 b2 = *(const bf16x8*)(r0 + 2 * N3D);
    bf16x8 x2 = *(const bf16x8*)(r0 + 2 * N3D + 2 * CONV_DIM);
#pragma unroll
    for (int j = 0; j < 8; ++j) {
      win0[j] = (float)b0[j] * (float)x0[j];
      win1[j] = (float)b1[j] * (float)x1[j];
      win2[j] = (float)b2[j] * (float)x2[j];
    }
  }

  for (int t = t0; t < t0 + TT; ++t) {
    const u16* row = bcx + (size_t)(s * SEQ_LEN + t) * N3D + d8;
    bf16x8 bv = *(const bf16x8*)row;
    bf16x8 cv = *(const bf16x8*)(row + CONV_DIM);
    bf16x8 xv = *(const bf16x8*)(row + 2 * CONV_DIM);
    float bx[8];
#pragma unroll
    for (int j = 0; j < 8; ++j) bx[j] = (float)bv[j] * (float)xv[j];

    u32 pk[4];
#pragma unroll
    for (int j = 0; j < 4; ++j) {
      const int a = 2 * j, b = 2 * j + 1;
      float ya = (float)cv[a] * (w0[a]*win0[a] + w1[a]*win1[a] + w2[a]*win2[a] + w3[a]*bx[a]);
      float yb = (float)cv[b] * (w0[b]*win0[b] + w1[b]*win1[b] + w2[b]*win2[b] + w3[b]*bx[b]);
      pk[j] = (u32)f2bf(ya) | ((u32)f2bf(yb) << 16);
    }
    uint4 o; o.x = pk[0]; o.y = pk[1]; o.z = pk[2]; o.w = pk[3];
    *(uint4*)&y[(size_t)(s * SEQ_LEN + t) * CONV_DIM + d8] = o;

    if (t >= SEQ_LEN - 3) {
      float* st = states + (size_t)(s * 3 + (t - (SEQ_LEN - 3))) * CONV_DIM + d8;
      float4 s0v; s0v.x = bx[0]; s0v.y = bx[1]; s0v.z = bx[2]; s0v.w = bx[3];
      float4 s1v; s1v.x = bx[4]; s1v.y = bx[5]; s1v.z = bx[6]; s1v.w = bx[7];
      *(float4*)st = s0v;
      *(float4*)(st + 4) = s1v;
    }
#pragma unroll
    for (int j = 0; j < 8; ++j) { win0[j] = win1[j]; win1[j] = win2[j]; win2[j] = bx[j]; }
  }
}

// ---------------- launch ----------------
extern "C" void kernel_launch(void* const* d_in, const int* in_sizes, int n_in,
                              void* d_out, int out_size, void* d_ws, size_t ws_size,
                              hipStream_t stream)
{
  const float* hidden = (const float*)d_in[0];  // [16384, 2048]
  const float* w_in   = (const float*)d_in[1];  // [6144, 2048]
  const float* convw  = (const float*)d_in[2];  // [2048, 1, 4]
  const float* w_out  = (const float*)d_in[3];  // [2048, 2048]

  char* ws = (char*)d_ws;
  u16* hb  = (u16*)(ws);                          // 33554432 elems (67.1 MB)
  u16* wib = (u16*)(ws + (size_t)67108864);       // 12582912 elems (25.2 MB)
  u16* wob = (u16*)(ws + (size_t)92274688);       //  4194304 elems ( 8.4 MB)
  u16* bcx = (u16*)(ws + (size_t)100663296);      // 16384*6144 elems (201 MB)
  u16* yb  = (u16*)(ws + (size_t)301989888);      // 33554432 elems (67.1 MB)

  float* out    = (float*)d_out;                  // [16384, 2048] fp32
  float* states = out + (size_t)NTOK * HIDDEN;    // [4, 3, 2048] fp32

  cast_f32_bf16<<<32768, 256, 0, stream>>>(hidden, hb, 8388608);
  cast_f32_bf16<<<12288, 256, 0, stream>>>(w_in,  wib, 3145728);
  cast_f32_bf16<<<4096,  256, 0, stream>>>(w_out, wob, 1048576);

  // bcx[N,6144] = hidden @ w_in^T  (bf16 out) — 24 x 64 = 1536 blocks
  gemm256_bt<true><<<dim3(N3D / 256, NTOK / 256), 512, 0, stream>>>(
      hb, wib, bcx, NTOK, N3D, HIDDEN);

  // depthwise conv + gates -> y bf16, states fp32
  conv_gate<<<dim3(SEQ_LEN / TT, NUM_SEQS), 256, 0, stream>>>(bcx, convw, yb, states);

  // out[N,2048] = y @ w_out^T  (fp32 out) — 8 x 64 = 512 blocks
  gemm256_bt<false><<<dim3(CONV_DIM / 256, NTOK / 256), 512, 0, stream>>>(
      yb, wob, out, NTOK, CONV_DIM, CONV_DIM);
}

// Round 6
// 933.147 us; speedup vs baseline: 1.0290x; 1.0290x over previous
//
#include <hip/hip_runtime.h>
#include <stdint.h>

#define NUM_SEQS 4
#define SEQ_LEN  4096
#define HIDDEN   2048
#define CONV_DIM 2048
#define NTOK     (NUM_SEQS * SEQ_LEN)
#define N3D      (3 * CONV_DIM)

typedef unsigned short u16;
typedef unsigned int   u32;
typedef __bf16 bf16x8 __attribute__((ext_vector_type(8)));
typedef float  f32x16 __attribute__((ext_vector_type(16)));

__device__ __forceinline__ u16 f2bf(float f) {
  union { float f; u32 u; } v; v.f = f;
  u32 u = v.u;
  u += 0x7fffu + ((u >> 16) & 1u);   // round-to-nearest-even
  return (u16)(u >> 16);
}

__device__ __forceinline__ void async16(const void* g, void* l) {
  __builtin_amdgcn_global_load_lds(
      (const __attribute__((address_space(1))) u32*)g,
      (__attribute__((address_space(3))) u32*)l, 16, 0, 0);
}

// ---------------- fp32 -> bf16 cast (vectorized) ----------------
__global__ __launch_bounds__(256) void cast_f32_bf16(
    const float* __restrict__ in, u16* __restrict__ out, int n4)
{
  int i = blockIdx.x * 256 + threadIdx.x;
  if (i >= n4) return;
  float4 f = ((const float4*)in)[i];
  ushort4 o;
  o.x = f2bf(f.x); o.y = f2bf(f.y); o.z = f2bf(f.z); o.w = f2bf(f.w);
  ((ushort4*)out)[i] = o;
}

// ---------------- bf16 GEMM, C = A[M,K] * B[N,K]^T ----------------
// 256x256 tile, BK=64, 8 waves (2M x 4N), per-wave 128x64 as 4x2 frags of
// v_mfma_f32_32x32x16_bf16. Frag layouts (r1-r4 verified):
//   A/B: X[row=lane&31][k=8*(lane>>5)+j]; C/D: col=lane&31,
//   row=(r&3)+8*(r>>2)+4*(lane>>5).
// FRAGMENT-LINEAR LDS (r3-verified, 0 bank conflicts): each 32row x 16k frag
// is one contiguous 1KB block; lane l reads byte l*16 (stride-1 wave read).
//
// SINGLE-REGION K-LOOP (round-5/6 change; r5 bench was lost to GPU-acquire
// timeout, resubmitted unchanged): r1-r4 showed the 8-barrier/K-tile phase
// structure is latency-bound (wall 5663 cyc/K-tile vs MFMA 516 + LDS <2k):
// reads and MFMA sat in different barrier regions (strict alternation) and
// 3x sched_barrier(0)/phase pinned the scheduler (m141 failure mode). All
// intra-tile barriers were structurally unnecessary -- the 4 phases read one
// stable buffer. Now per K-tile:
//   STAGE tile t+1 (8 gload_lds) ; s_waitcnt vmcnt(8)  [stage(t) landed]
//   s_barrier                                          [publish buf[t&1]]
//   24 ds_read_b128 + 32 MFMA, compiler-scheduled (lgkmcnt auto-counted,
//     read issue overlaps MFMA -- the m97 "near-optimal" behavior)
//   s_barrier                  [all reads done before stage(t+2) overwrites]
// 2 barriers + 1 counted vmcnt per K-tile (never 0 mid-loop: the vmcnt(0)
// drain is what capped the m97-structure 256^2 variant at 792 TF).
// Hazards: stage(t+1)->buf^1 (not read this iter); stage(t+2)->buf[t&1]
// issues after bar2(t) which follows all reads(t) (lgkm-drained before
// their consuming MFMA). Cross-wave staging visibility: each wave passes
// its own vmcnt(8) before bar1, reads after bar1.
template<bool OUT_BF16>
__global__ __launch_bounds__(512, 2) void gemm256_bt(
    const u16* __restrict__ A, const u16* __restrict__ B, void* __restrict__ Cv,
    const int M, const int N, const int K)
{
  __shared__ u16 sm[65536];            // A: [0,32768) u16, B: [32768,65536)
  u16* ldsA = &sm[0];
  u16* ldsB = &sm[32768];

  const int tid  = threadIdx.x;
  const int lane = tid & 63;
  const int wave = tid >> 6;
  const int l32  = lane & 31;
  const int hl   = lane >> 5;
  const int wm   = wave >> 2;          // 0..1
  const int wn   = wave & 3;           // 0..3
  (void)M;

  // T1: bijective XCD swizzle (nwg % 8 == 0 for all our launches)
  const int gx  = gridDim.x;
  const int nwg = gx * gridDim.y;
  const int orig = blockIdx.y * gx + blockIdx.x;
  const int cpx  = nwg >> 3;
  const int swz  = (orig & 7) * cpx + (orig >> 3);
  const int nBase = (swz % gx) * 256;
  const int mBase = (swz / gx) * 256;

  const int NT = K >> 6;               // K-tiles of 64 (NT=32, even)

  // ---- staging geometry (fragment-linear, r3-verified): thread fills
  // slots tid (rows 0-63 of a half) and tid+512 (rows 64-127 via C1).
  // slot s: row = (s>>8&1)*32 + (s&31), granule = (s>>6&3)*2 + (s>>5&1).
  const int rowS = ((tid >> 8) & 1) * 32 + (tid & 31);
  const int gsel = ((tid >> 6) & 3) * 2 + ((tid >> 5) & 1);
  const u16* aTB = A + (size_t)(mBase + rowS) * K + gsel * 8;
  const u16* bTB = B + (size_t)(nBase + rowS) * K + gsel * 8;
  const size_t C1 = (size_t)64 * K;                 // +64 rows for slot t+512

#define STAGE(ldsO, gBase, tl, h) do {                                        \
    const int _b = (tl) & 1;                                                  \
    u16* _d = (ldsO) + _b * 16384 + (h) * 8192 + tid * 8;                     \
    const u16* _s = (gBase) + (size_t)(h) * 128 * K + (size_t)(tl) * 64;      \
    async16(_s, _d); async16(_s + C1, _d + 4096);                             \
  } while (0)
#define STAGE_TILE(tl) do {                                                   \
    STAGE(ldsA, aTB, tl, 0); STAGE(ldsA, aTB, tl, 1);                         \
    STAGE(ldsB, bTB, tl, 0); STAGE(ldsB, bTB, tl, 1);                         \
  } while (0)

  // ---- fragment reads: contiguous 1KB per (rowBlk g, ks) ----
  const int aG = wm * 4;               // A rowBlk base (g = aG + mt, mt 0..3)
  const int bG = wn * 2;               // B rowBlk base (g = bG + nt, nt 0..1)
  const int lo = lane * 8;
#define LDA(g, ks, b) (*(const bf16x8*)&ldsA[(b) * 16384 + (g) * 2048 + (ks) * 512 + lo])
#define LDB(g, ks, b) (*(const bf16x8*)&ldsB[(b) * 16384 + (g) * 2048 + (ks) * 512 + lo])
#define MFMA(a, b, c) __builtin_amdgcn_mfma_f32_32x32x16_bf16((a), (b), (c), 0, 0, 0)

  f32x16 acc[4][2];
#pragma unroll
  for (int i = 0; i < 4; ++i)
#pragma unroll
    for (int j = 0; j < 2; ++j)
#pragma unroll
      for (int r = 0; r < 16; ++r) acc[i][j][r] = 0.f;

  // ---- prologue: stage tile 0 ----
  STAGE_TILE(0);

  for (int t2 = 0; t2 < NT; t2 += 2) {
#pragma unroll
    for (int u = 0; u < 2; ++u) {      // u == t & 1 (static buffer parity)
      const int t = t2 + u;

      if (t + 1 < NT) {
        STAGE_TILE(t + 1);
        asm volatile("s_waitcnt vmcnt(8)" ::: "memory");   // stage(t) landed
      } else {
        asm volatile("s_waitcnt vmcnt(0)" ::: "memory");
      }
      __builtin_amdgcn_s_barrier();    // buf[u] published to all waves

      bf16x8 aF[2][4], bF0[4], bF1[4];
#pragma unroll
      for (int ks = 0; ks < 4; ++ks) {
        aF[0][ks] = LDA(aG + 0, ks, u);
        aF[1][ks] = LDA(aG + 1, ks, u);
        bF0[ks]   = LDB(bG + 0, ks, u);
      }
#pragma unroll
      for (int ks = 0; ks < 4; ++ks) bF1[ks] = LDB(bG + 1, ks, u);

#pragma unroll
      for (int ks = 0; ks < 4; ++ks) {
        acc[0][0] = MFMA(aF[0][ks], bF0[ks], acc[0][0]);
        acc[1][0] = MFMA(aF[1][ks], bF0[ks], acc[1][0]);
      }
#pragma unroll
      for (int ks = 0; ks < 4; ++ks) {
        acc[0][1] = MFMA(aF[0][ks], bF1[ks], acc[0][1]);
        acc[1][1] = MFMA(aF[1][ks], bF1[ks], acc[1][1]);
      }

#pragma unroll
      for (int ks = 0; ks < 4; ++ks) {
        aF[0][ks] = LDA(aG + 2, ks, u);
        aF[1][ks] = LDA(aG + 3, ks, u);
      }
#pragma unroll
      for (int ks = 0; ks < 4; ++ks) {
        acc[2][1] = MFMA(aF[0][ks], bF1[ks], acc[2][1]);
        acc[3][1] = MFMA(aF[1][ks], bF1[ks], acc[3][1]);
      }
#pragma unroll
      for (int ks = 0; ks < 4; ++ks) {
        acc[2][0] = MFMA(aF[0][ks], bF0[ks], acc[2][0]);
        acc[3][0] = MFMA(aF[1][ks], bF0[ks], acc[3][0]);
      }

      __builtin_amdgcn_s_barrier();    // all reads(t) done before stage(t+2)
    }
  }
#undef STAGE
#undef STAGE_TILE
#undef LDA
#undef LDB
#undef MFMA

  // ---- epilogue: C/D col=lane&31, row=(r&3)+8*(r>>2)+4*(lane>>5) ----
#pragma unroll
  for (int mt = 0; mt < 4; ++mt) {
#pragma unroll
    for (int nt = 0; nt < 2; ++nt) {
      const int col = nBase + wn * 64 + nt * 32 + l32;
#pragma unroll
      for (int r = 0; r < 16; ++r) {
        const int row = mBase + wm * 128 + mt * 32 + (r & 3) + 8 * (r >> 2) + 4 * hl;
        if (OUT_BF16)
          ((u16*)Cv)[(size_t)row * N + col] = f2bf(acc[mt][nt][r]);
        else
          ((float*)Cv)[(size_t)row * N + col] = acc[mt][nt][r];
      }
    }
  }
}

// ---------------- causal depthwise conv (K=4) + gating ----------------
#define TT 32
__global__ __launch_bounds__(256) void conv_gate(
    const u16* __restrict__ bcx, const float* __restrict__ convw,
    u16* __restrict__ y, float* __restrict__ states)
{
  const int tid = threadIdx.x;
  const int d8  = tid * 8;
  const int s   = blockIdx.y;
  const int t0  = blockIdx.x * TT;

  float w0[8], w1[8], w2[8], w3[8];
#pragma unroll
  for (int j = 0; j < 8; ++j) {
    float4 wv = *(const float4*)&convw[(d8 + j) * 4];
    w0[j] = wv.x; w1[j] = wv.y; w2[j] = wv.z; w3[j] = wv.w;
  }

  float win0[8], win1[8], win2[8];
  if (t0 == 0) {
#pragma unroll
    for (int j = 0; j < 8; ++j) { win0[j] = 0.f; win1[j] = 0.f; win2[j] = 0.f; }
  } else {
    const u16* r0 = bcx + (size_t)(s * SEQ_LEN + t0 - 3) * N3D + d8;
    bf16x8 b0 = *(const bf16x8*)(r0);
    bf16x8 x0 = *(const bf16x8*)(r0 + 2 * CONV_DIM);
    bf16x8 b1 = *(const bf16x8*)(r0 + N3D);
    bf16x8 x1 = *(const bf16x8*)(r0 + N3D + 2 * CONV_DIM);
    bf16x8 b2 = *(const bf16x8*)(r0 + 2 * N3D);
    bf16x8 x2 = *(const bf16x8*)(r0 + 2 * N3D + 2 * CONV_DIM);
#pragma unroll
    for (int j = 0; j < 8; ++j) {
      win0[j] = (float)b0[j] * (float)x0[j];
      win1[j] = (float)b1[j] * (float)x1[j];
      win2[j] = (float)b2[j] * (float)x2[j];
    }
  }

  for (int t = t0; t < t0 + TT; ++t) {
    const u16* row = bcx + (size_t)(s * SEQ_LEN + t) * N3D + d8;
    bf16x8 bv = *(const bf16x8*)row;
    bf16x8 cv = *(const bf16x8*)(row + CONV_DIM);
    bf16x8 xv = *(const bf16x8*)(row + 2 * CONV_DIM);
    float bx[8];
#pragma unroll
    for (int j = 0; j < 8; ++j) bx[j] = (float)bv[j] * (float)xv[j];

    u32 pk[4];
#pragma unroll
    for (int j = 0; j < 4; ++j) {
      const int a = 2 * j, b = 2 * j + 1;
      float ya = (float)cv[a] * (w0[a]*win0[a] + w1[a]*win1[a] + w2[a]*win2[a] + w3[a]*bx[a]);
      float yb = (float)cv[b] * (w0[b]*win0[b] + w1[b]*win1[b] + w2[b]*win2[b] + w3[b]*bx[b]);
      pk[j] = (u32)f2bf(ya) | ((u32)f2bf(yb) << 16);
    }
    uint4 o; o.x = pk[0]; o.y = pk[1]; o.z = pk[2]; o.w = pk[3];
    *(uint4*)&y[(size_t)(s * SEQ_LEN + t) * CONV_DIM + d8] = o;

    if (t >= SEQ_LEN - 3) {
      float* st = states + (size_t)(s * 3 + (t - (SEQ_LEN - 3))) * CONV_DIM + d8;
      float4 s0v; s0v.x = bx[0]; s0v.y = bx[1]; s0v.z = bx[2]; s0v.w = bx[3];
      float4 s1v; s1v.x = bx[4]; s1v.y = bx[5]; s1v.z = bx[6]; s1v.w = bx[7];
      *(float4*)st = s0v;
      *(float4*)(st + 4) = s1v;
    }
#pragma unroll
    for (int j = 0; j < 8; ++j) { win0[j] = win1[j]; win1[j] = win2[j]; win2[j] = bx[j]; }
  }
}

// ---------------- launch ----------------
extern "C" void kernel_launch(void* const* d_in, const int* in_sizes, int n_in,
                              void* d_out, int out_size, void* d_ws, size_t ws_size,
                              hipStream_t stream)
{
  const float* hidden = (const float*)d_in[0];  // [16384, 2048]
  const float* w_in   = (const float*)d_in[1];  // [6144, 2048]
  const float* convw  = (const float*)d_in[2];  // [2048, 1, 4]
  const float* w_out  = (const float*)d_in[3];  // [2048, 2048]

  char* ws = (char*)d_ws;
  u16* hb  = (u16*)(ws);                          // 33554432 elems (67.1 MB)
  u16* wib = (u16*)(ws + (size_t)67108864);       // 12582912 elems (25.2 MB)
  u16* wob = (u16*)(ws + (size_t)92274688);       //  4194304 elems ( 8.4 MB)
  u16* bcx = (u16*)(ws + (size_t)100663296);      // 16384*6144 elems (201 MB)
  u16* yb  = (u16*)(ws + (size_t)301989888);      // 33554432 elems (67.1 MB)

  float* out    = (float*)d_out;                  // [16384, 2048] fp32
  float* states = out + (size_t)NTOK * HIDDEN;    // [4, 3, 2048] fp32

  cast_f32_bf16<<<32768, 256, 0, stream>>>(hidden, hb, 8388608);
  cast_f32_bf16<<<12288, 256, 0, stream>>>(w_in,  wib, 3145728);
  cast_f32_bf16<<<4096,  256, 0, stream>>>(w_out, wob, 1048576);

  // bcx[N,6144] = hidden @ w_in^T  (bf16 out) — 24 x 64 = 1536 blocks
  gemm256_bt<true><<<dim3(N3D / 256, NTOK / 256), 512, 0, stream>>>(
      hb, wib, bcx, NTOK, N3D, HIDDEN);

  // depthwise conv + gates -> y bf16, states fp32
  conv_gate<<<dim3(SEQ_LEN / TT, NUM_SEQS), 256, 0, stream>>>(bcx, convw, yb, states);

  // out[N,2048] = y @ w_out^T  (fp32 out) — 8 x 64 = 512 blocks
  gemm256_bt<false><<<dim3(CONV_DIM / 256, NTOK / 256), 512, 0, stream>>>(
      yb, wob, out, NTOK, CONV_DIM, CONV_DIM);
}